// Round 3
// baseline (5847.482 us; speedup 1.0000x reference)
//
#include <hip/hip_runtime.h>
#include <cstdint>
#include <cstddef>

#define DI __device__ __forceinline__

typedef uint16_t u16;
typedef __bf16 bf16x8 __attribute__((ext_vector_type(8)));
typedef float f32x4 __attribute__((ext_vector_type(4)));

DI float b2f(u16 u) { uint32_t x = ((uint32_t)u) << 16; float f; __builtin_memcpy(&f, &x, 4); return f; }
DI u16 f2b(float f) {
    uint32_t x; __builtin_memcpy(&x, &f, 4);
    uint32_t r = (x + 0x7FFFu + ((x >> 16) & 1u)) >> 16;
    return (u16)r;
}

// Canary: fill d_out (f32) with 100+ws_MiB; final GEMM overwrites everything.
__global__ __launch_bounds__(256) void canary_kernel(float* __restrict__ out, float val) {
    size_t idx = (size_t)blockIdx.x * 256 + threadIdx.x;
    out[idx] = val;
}

// ---------------------------------------------------------------------------
// Small-weight transpose + f32->bf16 convert
// ---------------------------------------------------------------------------
__global__ __launch_bounds__(256) void transpose_weights(
    const float* __restrict__ tmw1, const float* __restrict__ tdw1,
    const float* __restrict__ tdw2, const float* __restrict__ tmw2,
    u16* __restrict__ tmw1T, u16* __restrict__ tdw1T,
    u16* __restrict__ tdw2T, u16* __restrict__ tmw2T)
{
    int idx = blockIdx.x * 256 + threadIdx.x;
    if (idx < 327680) { int r = idx / 160, c = idx % 160; tmw1T[c * 2048 + r] = f2b(tmw1[idx]); return; }
    idx -= 327680;
    if (idx < 131072) { int r = idx / 64, c = idx % 64; tdw1T[c * 2048 + r] = f2b(tdw1[idx]); return; }
    idx -= 131072;
    if (idx < 131072) { int e = idx / 2048, c = idx % 2048; tdw2T[c * 64 + e] = f2b(tdw2[idx]); return; }
    idx -= 131072;
    { int f = idx / 65536; int rem = idx % 65536; int e = rem / 2048, c = rem % 2048;
      tmw2T[f * 65536 + c * 32 + e] = f2b(tmw2[idx]); }
}

DI float block_sum(float v, float* sm) {
    #pragma unroll
    for (int off = 32; off; off >>= 1) v += __shfl_xor(v, off, 64);
    __syncthreads();
    if ((threadIdx.x & 63) == 0) sm[threadIdx.x >> 6] = v;
    __syncthreads();
    float r = sm[0] + sm[1] + sm[2] + sm[3];
    __syncthreads();
    return r;
}

// LN0 then LN1 fused: x_in(f32) -> x0b (bf16 residual), xa (bf16)
__global__ __launch_bounds__(256) void ln01_kernel(
    const float* __restrict__ xin,
    const float* __restrict__ w0, const float* __restrict__ b0,
    const float* __restrict__ w1, const float* __restrict__ b1,
    u16* __restrict__ x0b, u16* __restrict__ xa)
{
    __shared__ float sm[4];
    int row = blockIdx.x;
    int tid = threadIdx.x;
    const float* xr = xin + (size_t)row * 2048;
    float v[8];
    float s = 0.f;
    #pragma unroll
    for (int i = 0; i < 8; i++) { v[i] = xr[tid + i * 256]; s += v[i]; }
    s = block_sum(s, sm);
    float mean = s * (1.f / 2048.f);
    float q = 0.f;
    #pragma unroll
    for (int i = 0; i < 8; i++) { float d = v[i] - mean; q += d * d; }
    q = block_sum(q, sm);
    float rstd = rsqrtf(q * (1.f / 2048.f) + 1e-5f);
    float t[8];
    float s2 = 0.f;
    #pragma unroll
    for (int i = 0; i < 8; i++) {
        int c = tid + i * 256;
        t[i] = (v[i] - mean) * rstd * w0[c] + b0[c];
        x0b[(size_t)row * 2048 + c] = f2b(t[i]);
        s2 += t[i];
    }
    s2 = block_sum(s2, sm);
    float mean2 = s2 * (1.f / 2048.f);
    float q2 = 0.f;
    #pragma unroll
    for (int i = 0; i < 8; i++) { float d = t[i] - mean2; q2 += d * d; }
    q2 = block_sum(q2, sm);
    float rstd2 = rsqrtf(q2 * (1.f / 2048.f) + 1e-5f);
    #pragma unroll
    for (int i = 0; i < 8; i++) {
        int c = tid + i * 256;
        xa[(size_t)row * 2048 + c] = f2b((t[i] - mean2) * rstd2 * w1[c] + b1[c]);
    }
}

// LN over bf16 input, f32 weights -> bf16 out (LN2)
__global__ __launch_bounds__(256) void ln_bf16_kernel(
    const u16* __restrict__ xin,
    const float* __restrict__ w, const float* __restrict__ b,
    u16* __restrict__ xout)
{
    __shared__ float sm[4];
    int row = blockIdx.x;
    int tid = threadIdx.x;
    const u16* xr = xin + (size_t)row * 2048;
    float v[8];
    float s = 0.f;
    #pragma unroll
    for (int i = 0; i < 8; i++) { v[i] = b2f(xr[tid + i * 256]); s += v[i]; }
    s = block_sum(s, sm);
    float mean = s * (1.f / 2048.f);
    float q = 0.f;
    #pragma unroll
    for (int i = 0; i < 8; i++) { float d = v[i] - mean; q += d * d; }
    q = block_sum(q, sm);
    float rstd = rsqrtf(q * (1.f / 2048.f) + 1e-5f);
    #pragma unroll
    for (int i = 0; i < 8; i++) {
        int c = tid + i * 256;
        xout[(size_t)row * 2048 + c] = f2b((v[i] - mean) * rstd * w[c] + b[c]);
    }
}

// xxx = xa + (shift(xa)-xa)*maa_x
__global__ __launch_bounds__(256) void ew_xxx(
    const u16* __restrict__ xa, const float* __restrict__ maax, u16* __restrict__ xxx)
{
    size_t idx = (size_t)blockIdx.x * 256 + threadIdx.x;
    int c = (int)(idx & 2047);
    int row = (int)(idx >> 11);
    float cur = b2f(xa[idx]);
    float prev = (row & 2047) ? b2f(xa[idx - 2048]) : 0.f;
    xxx[idx] = f2b(cur + (prev - cur) * maax[c]);
}

// xk2 / xr2 for CMix
__global__ __launch_bounds__(256) void ew_shift2(
    const u16* __restrict__ xf, const float* __restrict__ cmk, const float* __restrict__ cmr,
    u16* __restrict__ xk2, u16* __restrict__ xr2)
{
    size_t idx = (size_t)blockIdx.x * 256 + threadIdx.x;
    int c = (int)(idx & 2047);
    int row = (int)(idx >> 11);
    float cur = b2f(xf[idx]);
    float prev = (row & 2047) ? b2f(xf[idx - 2048]) : 0.f;
    float xx = prev - cur;
    xk2[idx] = f2b(cur + xx * cmk[c]);
    xr2[idx] = f2b(cur + xx * cmr[c]);
}

// GroupNorm(64 per head) * lnx + bias, then * g  -> Ao (bf16)
__global__ __launch_bounds__(256) void gn_kernel(
    const float* __restrict__ y, const u16* __restrict__ g,
    const float* __restrict__ lw, const float* __restrict__ lb,
    u16* __restrict__ Ao)
{
    int grp = blockIdx.x * 4 + (threadIdx.x >> 6);
    int m = threadIdx.x & 63;
    int h = grp & 31;
    size_t idx = (size_t)grp * 64 + m;
    float v = y[idx];
    float s = v;
    #pragma unroll
    for (int off = 32; off; off >>= 1) s += __shfl_xor(s, off, 64);
    float mean = s * (1.f / 64.f);
    float d = v - mean;
    float q = d * d;
    #pragma unroll
    for (int off = 32; off; off >>= 1) q += __shfl_xor(q, off, 64);
    float rstd = rsqrtf(q * (1.f / 64.f) + 6.4e-4f);   // eps = 1e-5 * 8^2
    float yn = d * rstd * lw[h * 64 + m] + lb[h * 64 + m];
    Ao[idx] = f2b(yn * b2f(g[idx]));
}

// ---------------------------------------------------------------------------
// WKV6 scan: one wave per (b,h); S[n][m] in lane m's registers (n = 0..63).
// w input is bf16 PRE-activation; decay exp(-exp(w)) computed fp32 here.
// ---------------------------------------------------------------------------
__global__ __launch_bounds__(64) void wkv_kernel(
    const u16* __restrict__ rb, const u16* __restrict__ kb, const u16* __restrict__ vb,
    const u16* __restrict__ wb, const float* __restrict__ ub, float* __restrict__ yb)
{
    int bh = blockIdx.x;
    int b = bh >> 5, h = bh & 31;
    int m = threadIdx.x;
    __shared__ __align__(16) float rs[64];
    __shared__ __align__(16) float ks[64];
    __shared__ __align__(16) float ws[64];
    float u_m = ub[h * 64 + m];
    float S[64];
    #pragma unroll
    for (int n = 0; n < 64; n++) S[n] = 0.f;
    size_t base = ((size_t)b * 2048) * 2048 + (size_t)h * 64 + m;
    float rc = b2f(rb[base]), kc = b2f(kb[base]), vc = b2f(vb[base]);
    float wc = __expf(-__expf(b2f(wb[base])));
    for (int t = 0; t < 2048; t++) {
        float rn = 0.f, kn = 0.f, vn = 0.f; u16 wn = 0;
        if (t < 2047) {
            size_t nidx = base + (size_t)(t + 1) * 2048;
            rn = b2f(rb[nidx]); kn = b2f(kb[nidx]); vn = b2f(vb[nidx]); wn = wb[nidx];
        }
        rs[m] = rc; ks[m] = kc; ws[m] = wc;
        __syncthreads();
        float p = rc * u_m * kc;
        #pragma unroll
        for (int off = 32; off; off >>= 1) p += __shfl_xor(p, off, 64);
        float y = p * vc;
        #pragma unroll
        for (int g4 = 0; g4 < 16; g4++) {
            float4 r4 = *(const float4*)&rs[g4 * 4];
            float4 k4 = *(const float4*)&ks[g4 * 4];
            float4 w4 = *(const float4*)&ws[g4 * 4];
            y += r4.x * S[g4 * 4 + 0] + r4.y * S[g4 * 4 + 1]
               + r4.z * S[g4 * 4 + 2] + r4.w * S[g4 * 4 + 3];
            S[g4 * 4 + 0] = S[g4 * 4 + 0] * w4.x + k4.x * vc;
            S[g4 * 4 + 1] = S[g4 * 4 + 1] * w4.y + k4.y * vc;
            S[g4 * 4 + 2] = S[g4 * 4 + 2] * w4.z + k4.z * vc;
            S[g4 * 4 + 3] = S[g4 * 4 + 3] * w4.w + k4.w * vc;
        }
        yb[base + (size_t)t * 2048] = y;
        __syncthreads();
        rc = rn; kc = kn; vc = vn; wc = __expf(-__expf(b2f(wn)));
    }
}

// ---------------------------------------------------------------------------
// GEMM: C[M,N] = A[M,K](bf16) * W[N,K]^T.  BF32=1: W is f32, converted to
// bf16 during LDS staging. 128x128 tile, BK=32, mfma_f32_16x16x32_bf16.
// MODE: 0 plain, 1 silu, 2 relu^2, 3 sigmoid, 4 tanh,
//       5 f32bias+acc->bf16 (decay pre-act), 6 token-shift mix,
//       7 residual-add bf16, 8 final f32: x1 + s*acc
// ---------------------------------------------------------------------------
template<int MODE, int BF32>
__global__ __launch_bounds__(256)
void gemm_bt(const u16* __restrict__ A, int lda,
             const u16* __restrict__ Bh, const float* __restrict__ Bf, int ldb,
             int N, int K,
             u16* __restrict__ Cb, float* __restrict__ Cf, int ldc,
             const u16* __restrict__ auxb0,
             const u16* __restrict__ auxb1,
             const float* __restrict__ auxf0)
{
    __shared__ __align__(16) u16 At[128 * 32];
    __shared__ __align__(16) u16 Bt[128 * 32];
    const int tid = threadIdx.x;
    const int lane = tid & 63;
    const int wv = tid >> 6;
    const int wr = wv >> 1, wc = wv & 1;
    const int m0 = blockIdx.y * 128;
    const int n0 = blockIdx.x * 128;
    const int l15 = lane & 15;
    const int lq = lane >> 4;
    f32x4 acc[4][4];
    #pragma unroll
    for (int i = 0; i < 4; i++)
        #pragma unroll
        for (int j = 0; j < 4; j++) acc[i][j] = (f32x4){0.f, 0.f, 0.f, 0.f};

    for (int k0 = 0; k0 < K; k0 += 32) {
        #pragma unroll
        for (int i = 0; i < 2; i++) {
            int s = tid + i * 256;
            int row = s >> 2, kc = s & 3;
            const u16* ga = A + (size_t)(m0 + row) * lda + k0 + kc * 8;
            uint4 av = *(const uint4*)ga;
            int brow = n0 + row; brow = brow < N ? brow : N - 1;
            uint4 bv;
            if (BF32) {
                const float* gb = Bf + (size_t)brow * ldb + k0 + kc * 8;
                float4 f0 = *(const float4*)gb;
                float4 f1 = *(const float4*)(gb + 4);
                uint32_t w0 = (uint32_t)f2b(f0.x) | ((uint32_t)f2b(f0.y) << 16);
                uint32_t w1 = (uint32_t)f2b(f0.z) | ((uint32_t)f2b(f0.w) << 16);
                uint32_t w2 = (uint32_t)f2b(f1.x) | ((uint32_t)f2b(f1.y) << 16);
                uint32_t w3 = (uint32_t)f2b(f1.z) | ((uint32_t)f2b(f1.w) << 16);
                bv = make_uint4(w0, w1, w2, w3);
            } else {
                const u16* gb = Bh + (size_t)brow * ldb + k0 + kc * 8;
                bv = *(const uint4*)gb;
            }
            *(uint4*)&At[(size_t)s * 8] = av;
            *(uint4*)&Bt[(size_t)s * 8] = bv;
        }
        __syncthreads();
        bf16x8 af[4], bfr[4];
        #pragma unroll
        for (int mi = 0; mi < 4; mi++)
            af[mi] = *(const bf16x8*)(&At[(wr * 64 + mi * 16 + l15) * 32 + lq * 8]);
        #pragma unroll
        for (int ni = 0; ni < 4; ni++)
            bfr[ni] = *(const bf16x8*)(&Bt[(wc * 64 + ni * 16 + l15) * 32 + lq * 8]);
        #pragma unroll
        for (int mi = 0; mi < 4; mi++)
            #pragma unroll
            for (int ni = 0; ni < 4; ni++)
                acc[mi][ni] = __builtin_amdgcn_mfma_f32_16x16x32_bf16(af[mi], bfr[ni], acc[mi][ni], 0, 0, 0);
        __syncthreads();
    }

    #pragma unroll
    for (int ni = 0; ni < 4; ni++) {
        int col = n0 + wc * 64 + ni * 16 + l15;
        if (col >= N) continue;
        #pragma unroll
        for (int mi = 0; mi < 4; mi++) {
            int rowb = m0 + wr * 64 + mi * 16 + lq * 4;
            #pragma unroll
            for (int r = 0; r < 4; r++) {
                int row = rowb + r;
                float v = acc[mi][ni][r];
                size_t o = (size_t)row * ldc + col;
                if (MODE == 0) {
                    Cb[o] = f2b(v);
                } else if (MODE == 1) {
                    float sg = 1.f / (1.f + __expf(-v)); Cb[o] = f2b(v * sg);
                } else if (MODE == 2) {
                    float t = v > 0.f ? v : 0.f; Cb[o] = f2b(t * t);
                } else if (MODE == 3) {
                    Cb[o] = f2b(1.f / (1.f + __expf(-v)));
                } else if (MODE == 4) {
                    Cb[o] = f2b(tanhf(v));
                } else if (MODE == 5) {
                    Cb[o] = f2b(auxf0[col] + v);
                } else if (MODE == 6) {
                    float cur = b2f(auxb0[(size_t)row * 2048 + col]);
                    float prev = (row & 2047) ? b2f(auxb0[(size_t)(row - 1) * 2048 + col]) : 0.f;
                    Cb[o] = f2b(cur + (prev - cur) * (auxf0[col] + v));
                } else if (MODE == 7) {
                    Cb[o] = f2b(b2f(auxb0[o]) + v);
                } else if (MODE == 8) {
                    Cf[o] = b2f(auxb0[o]) + b2f(auxb1[o]) * v;
                }
            }
        }
    }
}

// ---------------------------------------------------------------------------
extern "C" void kernel_launch(void* const* d_in, const int* in_sizes, int n_in,
                              void* d_out, int out_size, void* d_ws, size_t ws_size,
                              hipStream_t stream)
{
    const float* x_in  = (const float*)d_in[0];
    const float* ln0w  = (const float*)d_in[1];
    const float* ln0b  = (const float*)d_in[2];
    const float* ln1w  = (const float*)d_in[3];
    const float* ln1b  = (const float*)d_in[4];
    const float* ln2w  = (const float*)d_in[5];
    const float* ln2b  = (const float*)d_in[6];
    const float* maax  = (const float*)d_in[7];
    const float* maa5  = (const float*)d_in[8];
    const float* tmw1  = (const float*)d_in[9];
    const float* tmw2  = (const float*)d_in[10];
    const float* td    = (const float*)d_in[11];
    const float* tdw1  = (const float*)d_in[12];
    const float* tdw2  = (const float*)d_in[13];
    const float* u_in  = (const float*)d_in[14];
    const float* Wr    = (const float*)d_in[15];
    const float* Wk    = (const float*)d_in[16];
    const float* Wv    = (const float*)d_in[17];
    const float* Wg    = (const float*)d_in[18];
    const float* Wo    = (const float*)d_in[19];
    const float* lnxw  = (const float*)d_in[20];
    const float* lnxb  = (const float*)d_in[21];
    const float* cmk   = (const float*)d_in[22];
    const float* cmr   = (const float*)d_in[23];
    const float* Wfk   = (const float*)d_in[24];
    const float* Wfr   = (const float*)d_in[25];
    const float* Wfv   = (const float*)d_in[26];

    const size_t MB = 1048576ULL;
    char* W = (char*)d_ws;
    u16*   xa    = (u16*)(W + 0 * MB);      // LN1 out; dead after last mix
    u16*   mslot = (u16*)(W + 32 * MB);     // xxx, then per-f mix output
    u16*   x0b   = (u16*)(W + 64 * MB);     // LN0 out (residual)
    u16*   rbuf  = (u16*)(W + 96 * MB);
    u16*   kbuf  = (u16*)(W + 128 * MB);
    u16*   vbuf  = (u16*)(W + 160 * MB);
    u16*   gbuf  = (u16*)(W + 192 * MB);
    u16*   wpre  = (u16*)(W + 224 * MB);    // bf16 pre-activation decay
    u16*   t5    = (u16*)(W + 256 * MB);    // [8192,160]
    u16*   tmw1T = (u16*)(W + 259 * MB);
    u16*   tdw1T = (u16*)(W + 260 * MB);
    u16*   tdw2T = (u16*)(W + 261 * MB);
    u16*   tmw2T = (u16*)(W + 262 * MB);
    u16*   hwb   = (u16*)(W + 263 * MB);    // [8192,64]
    // aliases (dead-range reuse):
    float* ybuf = (float*)(W + 0 * MB);     // 64MB over xa+mslot (dead post-mix)
    u16*   Ao   = rbuf;                     // post-wkv
    u16*   x1b  = kbuf;                     // post-wkv residual
    u16*   xf   = vbuf;                     // LN2 out
    u16*   xk2  = gbuf;
    u16*   xr2  = wpre;
    u16*   kf   = (u16*)(W + 0 * MB);       // [8192,7168] = 112MB over dead head
    u16*   sb   = vbuf;                     // sigmoid out (xf dead)

    dim3 blk(256);
    dim3 g1(1, 64), g2(2, 64), g16(16, 64), g56(56, 64);

    float canary = 100.0f + (float)(ws_size >> 20);
    canary_kernel<<<65536, blk, 0, stream>>>((float*)d_out, canary);

    transpose_weights<<<3584, blk, 0, stream>>>(tmw1, tdw1, tdw2, tmw2, tmw1T, tdw1T, tdw2T, tmw2T);
    ln01_kernel<<<8192, blk, 0, stream>>>(x_in, ln0w, ln0b, ln1w, ln1b, x0b, xa);
    ew_xxx<<<65536, blk, 0, stream>>>(xa, maax, mslot);

    // t5 = tanh(xxx @ tm_w1)   [8192,160]
    gemm_bt<4,0><<<g2, blk, 0, stream>>>(mslot, 2048, tmw1T, nullptr, 2048, 160, 2048,
                                         t5, nullptr, 160, nullptr, nullptr, nullptr);
    // f=0 (w): mix -> mslot; hw = tanh(xw @ td_w1); wpre = td + hw @ td_w2
    gemm_bt<6,0><<<g16, blk, 0, stream>>>(t5 + 0 * 32, 160, tmw2T + 0 * 65536, nullptr, 32, 2048, 32,
                                          mslot, nullptr, 2048, xa, nullptr, maa5 + 0 * 2048);
    gemm_bt<4,0><<<g1, blk, 0, stream>>>(mslot, 2048, tdw1T, nullptr, 2048, 64, 2048,
                                         hwb, nullptr, 64, nullptr, nullptr, nullptr);
    gemm_bt<5,0><<<g16, blk, 0, stream>>>(hwb, 64, tdw2T, nullptr, 64, 2048, 64,
                                          wpre, nullptr, 2048, nullptr, nullptr, td);
    // f=1 (k)
    gemm_bt<6,0><<<g16, blk, 0, stream>>>(t5 + 1 * 32, 160, tmw2T + 1 * 65536, nullptr, 32, 2048, 32,
                                          mslot, nullptr, 2048, xa, nullptr, maa5 + 1 * 2048);
    gemm_bt<0,1><<<g16, blk, 0, stream>>>(mslot, 2048, nullptr, Wk, 2048, 2048, 2048,
                                          kbuf, nullptr, 2048, nullptr, nullptr, nullptr);
    // f=2 (v)
    gemm_bt<6,0><<<g16, blk, 0, stream>>>(t5 + 2 * 32, 160, tmw2T + 2 * 65536, nullptr, 32, 2048, 32,
                                          mslot, nullptr, 2048, xa, nullptr, maa5 + 2 * 2048);
    gemm_bt<0,1><<<g16, blk, 0, stream>>>(mslot, 2048, nullptr, Wv, 2048, 2048, 2048,
                                          vbuf, nullptr, 2048, nullptr, nullptr, nullptr);
    // f=3 (r)
    gemm_bt<6,0><<<g16, blk, 0, stream>>>(t5 + 3 * 32, 160, tmw2T + 3 * 65536, nullptr, 32, 2048, 32,
                                          mslot, nullptr, 2048, xa, nullptr, maa5 + 3 * 2048);
    gemm_bt<0,1><<<g16, blk, 0, stream>>>(mslot, 2048, nullptr, Wr, 2048, 2048, 2048,
                                          rbuf, nullptr, 2048, nullptr, nullptr, nullptr);
    // f=4 (g): silu epilogue
    gemm_bt<6,0><<<g16, blk, 0, stream>>>(t5 + 4 * 32, 160, tmw2T + 4 * 65536, nullptr, 32, 2048, 32,
                                          mslot, nullptr, 2048, xa, nullptr, maa5 + 4 * 2048);
    gemm_bt<1,1><<<g16, blk, 0, stream>>>(mslot, 2048, nullptr, Wg, 2048, 2048, 2048,
                                          gbuf, nullptr, 2048, nullptr, nullptr, nullptr);

    // WKV scan -> y (fp32, overlays xa+mslot which are now dead)
    wkv_kernel<<<128, 64, 0, stream>>>(rbuf, kbuf, vbuf, wpre, u_in, ybuf);
    // GroupNorm * g -> Ao (over rbuf)
    gn_kernel<<<65536, blk, 0, stream>>>(ybuf, gbuf, lnxw, lnxb, Ao);
    // x1 = x0 + Ao @ Wo^T  (bf16, over kbuf)
    gemm_bt<7,1><<<g16, blk, 0, stream>>>(Ao, 2048, nullptr, Wo, 2048, 2048, 2048,
                                          x1b, nullptr, 2048, x0b, nullptr, nullptr);
    // CMix
    ln_bf16_kernel<<<8192, blk, 0, stream>>>(x1b, ln2w, ln2b, xf);
    ew_shift2<<<65536, blk, 0, stream>>>(xf, cmk, cmr, xk2, xr2);
    gemm_bt<2,1><<<g56, blk, 0, stream>>>(xk2, 2048, nullptr, Wfk, 2048, 7168, 2048,
                                          kf, nullptr, 7168, nullptr, nullptr, nullptr);
    gemm_bt<3,1><<<g16, blk, 0, stream>>>(xr2, 2048, nullptr, Wfr, 2048, 2048, 2048,
                                          sb, nullptr, 2048, nullptr, nullptr, nullptr);
    gemm_bt<8,1><<<g16, blk, 0, stream>>>(kf, 7168, nullptr, Wfv, 7168, 2048, 7168,
                                          nullptr, (float*)d_out, 2048, x1b, sb, nullptr);
}